// Round 1
// baseline (30.282 us; speedup 1.0000x reference)
//
#include <hip/hip_runtime.h>
#include <hip/hip_bf16.h>

#define BB 8
#define TT 2048
#define FF 64
#define LL 48
#define TB 64              // tokens per block
#define NW 8               // waves per block (512 threads)
#define TPW (TB / NW)      // tokens per wave
#define ROWS (TB + LL)     // staged he rows
#define PAD 65             // +1 pad: conflict-free row reads both ways

__global__ __launch_bounds__(NW * 64, 1)
void ContextBlock_kernel(const float* __restrict__ he,
                         const float* __restrict__ Wm,
                         const float* __restrict__ bias,
                         float* __restrict__ out)
{
    __shared__ float tile[ROWS * PAD];   // he[t0-48 .. t0+63, :], rows clamped to >= 0
    __shared__ float sW[FF * FF];        // W[g][f] row-major, unpadded (f-consecutive reads: 2-way alias, free)
    __shared__ float qs[NW][FF];         // per-wave q vector
    __shared__ float ws[NW][FF];         // per-wave softmax weights

    const int tid  = threadIdx.x;
    const int wave = tid >> 6;
    const int lane = tid & 63;
    const int b    = blockIdx.y;
    const int t0   = blockIdx.x * TB;

    const float* heb = he + (size_t)b * TT * FF;

    // stage W: 4096 floats / 512 threads = 8 each, coalesced
    #pragma unroll
    for (int e = tid; e < FF * FF; e += NW * 64) sW[e] = Wm[e];

    // stage he tile: 112 rows x 64, row index clamped at 0 (matches reference clip)
    #pragma unroll
    for (int e = tid; e < ROWS * FF; e += NW * 64) {
        int r = e >> 6, c = e & 63;
        int g = t0 - LL + r;
        g = g < 0 ? 0 : g;
        tile[r * PAD + c] = heb[(size_t)g * FF + c];
    }
    __syncthreads();

    const float bf = bias[lane];

    for (int i = 0; i < TPW; ++i) {
        const int lt0 = wave * TPW + i;   // token offset within block = t - t0
        const int t   = t0 + lt0;
        const int rt  = lt0 + LL;         // this token's row in tile

        // ---- q[lane] = bias + sum_g he[t][g] * W[g][lane] ----
        float q = bf;
        const float* hrow = &tile[rt * PAD];
        #pragma unroll
        for (int g = 0; g < FF; ++g)
            q = fmaf(hrow[g], sW[g * FF + lane], q);   // hrow[g]: broadcast; sW: 2-way alias (free)
        qs[wave][lane] = q;
        __builtin_amdgcn_wave_barrier();   // wave-synchronous LDS: same wave writes then reads

        // ---- scores: lane l computes win[l] . q ----
        const int lw = lane < LL ? lane : (LL - 1);    // keep OOB lanes in-range
        const float* wrow = &tile[(lt0 + lw) * PAD];
        float s = 0.f;
        #pragma unroll
        for (int f = 0; f < FF; ++f)
            s = fmaf(wrow[f], qs[wave][f], s);         // wrow: pad-65 => conflict-free; qs: broadcast
        const bool valid = (t == 0) ? (lane == LL - 1)
                                    : (lane < LL && (t - LL + lane) >= 0);
        if (!valid) s = -1e30f;

        // ---- masked softmax over 64 lanes (invalid lanes contribute exp -> 0) ----
        float m = s;
        #pragma unroll
        for (int off = 32; off; off >>= 1)
            m = fmaxf(m, __shfl_xor(m, off));
        float p = __expf(s - m);
        float sum = p;
        #pragma unroll
        for (int off = 32; off; off >>= 1)
            sum += __shfl_xor(sum, off);
        ws[wave][lane] = p / sum;
        __builtin_amdgcn_wave_barrier();

        // ---- ctx[lane] = sum_l w[l] * win[l][lane] ----
        float c = 0.f;
        #pragma unroll
        for (int l = 0; l < LL; ++l)
            c = fmaf(ws[wave][l], tile[(lt0 + l) * PAD + lane], c);  // ws: broadcast; tile: 2-way alias

        out[((size_t)b * TT + t) * FF + lane] = c;
    }
}

extern "C" void kernel_launch(void* const* d_in, const int* in_sizes, int n_in,
                              void* d_out, int out_size, void* d_ws, size_t ws_size,
                              hipStream_t stream) {
    const float* he   = (const float*)d_in[0];
    const float* Wm   = (const float*)d_in[1];
    const float* bias = (const float*)d_in[2];
    float* out        = (float*)d_out;

    dim3 grid(TT / TB, BB);   // 32 x 8 = 256 blocks
    ContextBlock_kernel<<<grid, NW * 64, 0, stream>>>(he, Wm, bias, out);
}

// Round 3
// 11.968 us; speedup vs baseline: 2.5303x; 2.5303x over previous
//
#include <hip/hip_runtime.h>
#include <hip/hip_bf16.h>

#define BB 8
#define TT 2048
#define FF 64
#define LL 48
#define TB 64            // tokens per block
#define RE 112           // extended He rows: t0-48 .. t0+63
#define NW 8
#define NT (NW * 64)

typedef __attribute__((ext_vector_type(8))) short bf16x8;   // MFMA A/B frag (8 bf16)
typedef __attribute__((ext_vector_type(4))) float f32x4;    // MFMA C/D frag

// LDS layout (bytes). All 2D tiles: row stride = chunks*16B, XOR-swizzled chunk ^= (row&7)
// (PT/HET rows have 16 chunks; 4-bit chunk index XOR 3-bit row bits is bijective per row).
#define HE_HI 0          // He_ext hi [112][64] bf16, 8 chunks/row (A-operand: rows=r_ext, k=f)
#define HE_LO 14336      // He_ext lo [112][64] bf16
#define WT_HI 28672      // W^T hi [64][64] bf16 (B-operand Q: rows=g, k=f)   [dead after phase 2]
#define WT_LO 36864      // W^T lo
#define QQ_HI 45056      // Q hi [64][64] bf16  (B-operand S: rows=tok, k=g)  [dead after phase 3]
#define QQ_LO 53248      // Q lo
// aliases, live from phase 4 on:
#define HET   28672      // He_extT [64][128] bf16, 16 chunks/row (B-operand ctx: rows=f, k=r_ext)
#define PT    45056      // P^T     [64][128] bf16, 16 chunks/row (A-operand ctx: rows=tok, k=r_ext)
#define RED   61440      // [64 tok][2 part][m,sum] f32 = 1024 B
#define SMEM_BYTES 62464

__device__ __forceinline__ unsigned short f2b(float x) {    // fp32 -> bf16 RNE
    unsigned int u = __builtin_bit_cast(unsigned int, x);
    return (unsigned short)((u + 0x7FFFu + ((u >> 16) & 1u)) >> 16);
}
__device__ __forceinline__ float b2f(unsigned short h) {
    return __builtin_bit_cast(float, (unsigned int)h << 16);
}

__global__ __launch_bounds__(NT, 1)
void ContextBlock_kernel(const float* __restrict__ he,
                         const float* __restrict__ Wm,
                         const float* __restrict__ bias,
                         float* __restrict__ out)
{
    __shared__ __align__(16) unsigned char smem[SMEM_BYTES];

    const int tid  = threadIdx.x;
    const int wave = tid >> 6;
    const int lane = tid & 63;
    const int bb   = blockIdx.y;
    const int t0   = blockIdx.x * TB;

    const float* heb = he + (size_t)bb * TT * FF;

    // ---- phase 1: stage He_ext (hi/lo, swizzled) + W^T (hi/lo) ----
    const float4* he4 = (const float4*)heb;
    for (int e = tid; e < RE * 16; e += NT) {               // 112 rows x 16 float4-chunks
        int r = e >> 4, c4 = e & 15;
        int g = t0 - LL + r; g = g < 0 ? 0 : g;             // clamp = reference's clip(rel,0,..)
        float4 v = he4[g * 16 + c4];
        unsigned short h0 = f2b(v.x), h1 = f2b(v.y), h2 = f2b(v.z), h3 = f2b(v.w);
        unsigned short l0 = f2b(v.x - b2f(h0)), l1 = f2b(v.y - b2f(h1));
        unsigned short l2 = f2b(v.z - b2f(h2)), l3 = f2b(v.w - b2f(h3));
        unsigned long long pkh = (unsigned long long)h0 | ((unsigned long long)h1 << 16)
                               | ((unsigned long long)h2 << 32) | ((unsigned long long)h3 << 48);
        unsigned long long pkl = (unsigned long long)l0 | ((unsigned long long)l1 << 16)
                               | ((unsigned long long)l2 << 32) | ((unsigned long long)l3 << 48);
        int off = r * 128 + ((((c4 >> 1) ^ (r & 7)) << 4)) + ((c4 & 1) << 3);
        *(unsigned long long*)(smem + HE_HI + off) = pkh;
        *(unsigned long long*)(smem + HE_LO + off) = pkl;
    }
    const float4* w4 = (const float4*)Wm;
    for (int e = tid; e < 1024; e += NT) {                  // W: 64x64 = 1024 float4-chunks
        int f = e >> 4, g4 = e & 15;
        float4 v = w4[e];
        float vv[4] = {v.x, v.y, v.z, v.w};
        #pragma unroll
        for (int i = 0; i < 4; ++i) {
            int g = g4 * 4 + i;
            unsigned short hi = f2b(vv[i]);
            unsigned short lo = f2b(vv[i] - b2f(hi));
            int off = g * 128 + ((((f >> 3) ^ (g & 7)) << 4)) + ((f & 7) << 1);
            *(unsigned short*)(smem + WT_HI + off) = hi;
            *(unsigned short*)(smem + WT_LO + off) = lo;
        }
    }
    __syncthreads();

    const int l15 = lane & 15;
    const int lhi = lane >> 4;

    // ---- phase 2: Q = He*W + b, split-bf16 (hi*hi + hi*lo + lo*hi) -> Q hi/lo ----
    #pragma unroll
    for (int s = 0; s < 2; ++s) {
        int q = wave * 2 + s;
        int mt = q >> 2, nt = q & 3;
        f32x4 acc = (f32x4){0.f, 0.f, 0.f, 0.f};
        int arow = LL + mt * 16 + l15;                      // He row of token
        int colg = nt * 16 + l15;
        #pragma unroll
        for (int kf = 0; kf < 2; ++kf) {
            int chunk = 4 * kf + lhi;
            int offA = arow * 128 + ((chunk ^ (arow & 7)) << 4);
            int offB = colg * 128 + ((chunk ^ (colg & 7)) << 4);
            bf16x8 ah = *(const bf16x8*)(smem + HE_HI + offA);
            bf16x8 al = *(const bf16x8*)(smem + HE_LO + offA);
            bf16x8 bh = *(const bf16x8*)(smem + WT_HI + offB);
            bf16x8 bl = *(const bf16x8*)(smem + WT_LO + offB);
            acc = __builtin_amdgcn_mfma_f32_16x16x32_bf16(ah, bh, acc, 0, 0, 0);
            acc = __builtin_amdgcn_mfma_f32_16x16x32_bf16(ah, bl, acc, 0, 0, 0);
            acc = __builtin_amdgcn_mfma_f32_16x16x32_bf16(al, bh, acc, 0, 0, 0);
        }
        float bv = bias[colg];
        #pragma unroll
        for (int i = 0; i < 4; ++i) {                       // C: row=tok=(lane>>4)*4+i, col=g
            int tok = mt * 16 + lhi * 4 + i;
            float qv = acc[i] + bv;
            unsigned short hi = f2b(qv);
            unsigned short lo = f2b(qv - b2f(hi));
            int off = tok * 128 + ((((colg >> 3) ^ (tok & 7)) << 4)) + ((colg & 7) << 1);
            *(unsigned short*)(smem + QQ_HI + off) = hi;
            *(unsigned short*)(smem + QQ_LO + off) = lo;
        }
    }
    __syncthreads();

    // ---- phase 3: scores S = He_ext * Q^T (split-bf16) + masked partial softmax ----
    const int ct = wave >> 1, pp = wave & 1;
    const int tok = ct * 16 + l15;                          // this lane's token column
    f32x4 sc[2];
    #pragma unroll
    for (int u = 0; u < 2; ++u) {
        int rt = ct + 2 * pp + u;
        f32x4 acc = (f32x4){0.f, 0.f, 0.f, 0.f};
        int arow = rt * 16 + l15;
        #pragma unroll
        for (int kf = 0; kf < 2; ++kf) {
            int chunk = 4 * kf + lhi;
            int offA = arow * 128 + ((chunk ^ (arow & 7)) << 4);
            int offB = tok * 128 + ((chunk ^ (tok & 7)) << 4);
            bf16x8 ah = *(const bf16x8*)(smem + HE_HI + offA);
            bf16x8 al = *(const bf16x8*)(smem + HE_LO + offA);
            bf16x8 bh = *(const bf16x8*)(smem + QQ_HI + offB);
            bf16x8 bl = *(const bf16x8*)(smem + QQ_LO + offB);
            acc = __builtin_amdgcn_mfma_f32_16x16x32_bf16(ah, bh, acc, 0, 0, 0);
            acc = __builtin_amdgcn_mfma_f32_16x16x32_bf16(ah, bl, acc, 0, 0, 0);
            acc = __builtin_amdgcn_mfma_f32_16x16x32_bf16(al, bh, acc, 0, 0, 0);
        }
        sc[u] = acc;
    }
    // mask: element (r_ext = 16rt + 4*lhi + i, token col = tok)
    float m = -1e30f;
    #pragma unroll
    for (int u = 0; u < 2; ++u) {
        int rt = ct + 2 * pp + u;
        #pragma unroll
        for (int i = 0; i < 4; ++i) {
            int r_ext = rt * 16 + lhi * 4 + i;
            int l = r_ext - tok;
            bool valid = (t0 == 0 && tok == 0) ? (r_ext == LL - 1)
                                               : (l >= 0 && l < LL && (t0 + r_ext) >= LL);
            float s = valid ? sc[u][i] : -1e30f;
            sc[u][i] = s;
            m = fmaxf(m, s);
        }
    }
    m = fmaxf(m, __shfl_xor(m, 16));
    m = fmaxf(m, __shfl_xor(m, 32));                        // column max over this wave's 2 rowtiles
    float sum = 0.f;
    #pragma unroll
    for (int u = 0; u < 2; ++u)
        #pragma unroll
        for (int i = 0; i < 4; ++i)
            sum += __expf(sc[u][i] - m);                    // all-invalid case killed in combine
    sum += __shfl_xor(sum, 16);
    sum += __shfl_xor(sum, 32);
    if (lane < 16) {
        float2 ms = make_float2(m, sum);
        *(float2*)(smem + RED + tok * 16 + pp * 8) = ms;
    }
    __syncthreads();

    // ---- phase 4: combine partials -> P^T; build He_extT from He_hi (WT/QQ now dead) ----
    {
        float2 p0 = *(const float2*)(smem + RED + tok * 16 + 0);
        float2 p1 = *(const float2*)(smem + RED + tok * 16 + 8);
        float M = fmaxf(p0.x, p1.x);
        float T = p0.y * __expf(p0.x - M) + p1.y * __expf(p1.x - M);
        float invT = 1.0f / T;
        #pragma unroll
        for (int u = 0; u < 2; ++u) {
            int rt = ct + 2 * pp + u;
            int rbase = rt * 16 + lhi * 4;                  // 4 consecutive r_ext
            unsigned short w0 = f2b(__expf(sc[u][0] - M) * invT);
            unsigned short w1 = f2b(__expf(sc[u][1] - M) * invT);
            unsigned short w2 = f2b(__expf(sc[u][2] - M) * invT);
            unsigned short w3 = f2b(__expf(sc[u][3] - M) * invT);
            unsigned long long pk = (unsigned long long)w0 | ((unsigned long long)w1 << 16)
                                  | ((unsigned long long)w2 << 32) | ((unsigned long long)w3 << 48);
            *(unsigned long long*)(smem + PT + tok * 256
                + ((((rbase >> 3) ^ (tok & 7)) << 4)) + ((rbase & 7) << 1)) = pk;
            // complementary rowtiles (rt+4)&7: zero (covers all 8 rowtiles per token row)
            int zbase = (((rt + 4) & 7) * 16) + lhi * 4;
            *(unsigned long long*)(smem + PT + tok * 256
                + ((((zbase >> 3) ^ (tok & 7)) << 4)) + ((zbase & 7) << 1)) = 0ull;
        }
    }
    // He_extT[f][r] <- He_hi[r][f]  (LDS transpose; one-time)
    for (int e = tid; e < RE * 64; e += NT) {
        int r = e >> 6, f = e & 63;
        unsigned short h = *(const unsigned short*)
            (smem + HE_HI + r * 128 + ((((f >> 3) ^ (r & 7)) << 4)) + ((f & 7) << 1));
        *(unsigned short*)
            (smem + HET + f * 256 + ((((r >> 3) ^ (f & 7)) << 4)) + ((r & 7) << 1)) = h;
    }
    if (tid < 128) {                                        // zero pad: logical chunks 14,15 (k=112..127)
        int f = tid >> 1, c = 14 + (tid & 1);
        *(f32x4*)(smem + HET + f * 256 + ((c ^ (f & 7)) << 4)) = (f32x4){0.f, 0.f, 0.f, 0.f};
    }
    __syncthreads();

    // ---- phase 5: ctx = P^T * He_ext (banded K, hi-only) -> global ----
    #pragma unroll
    for (int s2 = 0; s2 < 2; ++s2) {
        int t = wave * 2 + s2;
        int mt = t >> 2, nt = t & 3;
        f32x4 acc = (f32x4){0.f, 0.f, 0.f, 0.f};
        int arow = mt * 16 + l15;                           // P^T row = token
        int brow = nt * 16 + l15;                           // He^T row = f
        int kf0 = mt >> 1;
        int nkf = (mt & 1) ? 3 : 2;                         // K chunks covering r_ext in [16mt, 16mt+64)
        for (int kk = 0; kk < nkf; ++kk) {
            int chunk = 4 * (kf0 + kk) + lhi;
            bf16x8 a  = *(const bf16x8*)(smem + PT  + arow * 256 + ((chunk ^ (arow & 7)) << 4));
            bf16x8 bo = *(const bf16x8*)(smem + HET + brow * 256 + ((chunk ^ (brow & 7)) << 4));
            acc = __builtin_amdgcn_mfma_f32_16x16x32_bf16(a, bo, acc, 0, 0, 0);
        }
        #pragma unroll
        for (int i = 0; i < 4; ++i) {
            int tk = mt * 16 + lhi * 4 + i;
            out[((size_t)bb * TT + t0 + tk) * FF + nt * 16 + l15] = acc[i];
        }
    }
}

extern "C" void kernel_launch(void* const* d_in, const int* in_sizes, int n_in,
                              void* d_out, int out_size, void* d_ws, size_t ws_size,
                              hipStream_t stream) {
    const float* he   = (const float*)d_in[0];
    const float* Wm   = (const float*)d_in[1];
    const float* bias = (const float*)d_in[2];
    float* out        = (float*)d_out;

    dim3 grid(TT / TB, BB);   // 32 x 8 = 256 blocks, ~1 per CU
    ContextBlock_kernel<<<grid, NT, 0, stream>>>(he, Wm, bias, out);
}